// Round 1
// 182.476 us; speedup vs baseline: 1.0991x; 1.0991x over previous
//
#include <hip/hip_runtime.h>
#include <hip/hip_bf16.h>
#include <math.h>
#include <stdint.h>

#define N_ROWS 8192
#define DIM 512
#define INV_TAU 5.0f
#define EXP5 148.41315910257660342f   // exp(1/tau) = exp(5)

typedef float f32x4 __attribute__((ext_vector_type(4)));
typedef int   i32x4 __attribute__((ext_vector_type(4)));
typedef int   i32x8 __attribute__((ext_vector_type(8)));

union Frag8 {            // one K=128 fragment: 32 B/lane = 8 VGPRs
  i32x8 v8;
  struct { i32x4 lo, hi; } s;
};

__device__ __forceinline__ void gload_lds16(const void* g, void* l) {
  __builtin_amdgcn_global_load_lds(
      (__attribute__((address_space(1))) void*)(void*)g,
      (__attribute__((address_space(3))) void*)l,
      16, 0, 0);
}

// Block = 16 rows (one MFMA group), 256 threads. Thread t: row t>>4, k-span
// (t&15)*32..+31. Norms via 16-lane butterfly, fp32 diag dot, fp8 e4m3
// quantization into the K=128 MX-fragment packed layout:
//   unit (g=row/16, ks=k/128) = 2048 B, two lane-major halves:
//     h=0 @ +0   : lane l's bytes k=(l>>4)*32+ 0..15 (v[0:3])
//     h=1 @ +1024: lane l's bytes k=(l>>4)*32+16..31 (v[4:7])
//   lane l: row l&15. 8 KB per group per array. One frag = 2 int4 loads.
// Scatter goes through LDS so global writes are coalesced int4.
// Also zeroes r1/r2/brow/bcol/out.
__global__ __launch_bounds__(256) void normalize_kernel(
    const float* __restrict__ z1, const float* __restrict__ z2,
    uint8_t* __restrict__ h1p, uint8_t* __restrict__ h2p,
    float* __restrict__ dvec,
    float* __restrict__ r1, float* __restrict__ r2,
    float* __restrict__ brow, float* __restrict__ bcol,
    float* __restrict__ out) {
  __shared__ __align__(16) uint8_t L[16384];  // 8KB h1-part, 8KB h2-part
  const int t = threadIdx.x;
  const int lr = t >> 4;          // row in group 0..15
  const int kb = t & 15;          // this thread's 32-elem k-block
  const int row = blockIdx.x * 16 + lr;
  const float4* p1 = (const float4*)(z1 + (size_t)row * DIM + kb * 32);
  const float4* p2 = (const float4*)(z2 + (size_t)row * DIM + kb * 32);
  float4 a[8], b[8];
  float s1 = 0.f, s2 = 0.f, s3 = 0.f;
#pragma unroll
  for (int i = 0; i < 8; i++) {
    a[i] = p1[i]; b[i] = p2[i];
    s1 += a[i].x*a[i].x + a[i].y*a[i].y + a[i].z*a[i].z + a[i].w*a[i].w;
    s2 += b[i].x*b[i].x + b[i].y*b[i].y + b[i].z*b[i].z + b[i].w*b[i].w;
    s3 += a[i].x*b[i].x + a[i].y*b[i].y + a[i].z*b[i].z + a[i].w*b[i].w;
  }
  for (int m = 1; m <= 8; m <<= 1) {
    s1 += __shfl_xor(s1, m);
    s2 += __shfl_xor(s2, m);
    s3 += __shfl_xor(s3, m);
  }
  const float inv1 = 1.0f / fmaxf(sqrtf(s1), 1e-12f);
  const float inv2 = 1.0f / fmaxf(sqrtf(s2), 1e-12f);
  int w1[8], w2[8];
#pragma unroll
  for (int i = 0; i < 8; i++) {
    int w = __builtin_amdgcn_cvt_pk_fp8_f32(a[i].x*inv1, a[i].y*inv1, 0, false);
    w1[i] = __builtin_amdgcn_cvt_pk_fp8_f32(a[i].z*inv1, a[i].w*inv1, w, true);
    w = __builtin_amdgcn_cvt_pk_fp8_f32(b[i].x*inv2, b[i].y*inv2, 0, false);
    w2[i] = __builtin_amdgcn_cvt_pk_fp8_f32(b[i].z*inv2, b[i].w*inv2, w, true);
  }
  // K=128 packed LDS scatter: this k-block is unit ks=kb>>2, lane
  // l=(kb&3)*16+lr; first 16B -> h=0, last 16B -> h=1.
  const int ks = kb >> 2;
  const int l = (kb & 3) * 16 + lr;
  *(int4*)(L + ks * 2048 + l * 16)          = make_int4(w1[0], w1[1], w1[2], w1[3]);
  *(int4*)(L + ks * 2048 + 1024 + l * 16)   = make_int4(w1[4], w1[5], w1[6], w1[7]);
  *(int4*)(L + 8192 + ks * 2048 + l * 16)        = make_int4(w2[0], w2[1], w2[2], w2[3]);
  *(int4*)(L + 8192 + ks * 2048 + 1024 + l * 16) = make_int4(w2[4], w2[5], w2[6], w2[7]);
  if (kb == 0) dvec[row] = s3 * inv1 * inv2;
  if (t < 16) {
    const int i = blockIdx.x * 16 + t;
    r1[i] = 0.f; r2[i] = 0.f; brow[i] = 0.f; bcol[i] = 0.f;
    if (i == 0) out[0] = 0.f;
  }
  __syncthreads();
  const size_t gb = (size_t)blockIdx.x * 8192;
  int4* g1 = (int4*)(h1p + gb);
  int4* g2 = (int4*)(h2p + gb);
  const int4* Lv = (const int4*)L;
  g1[t]       = Lv[t];
  g1[t + 256] = Lv[t + 256];
  g2[t]       = Lv[t + 512];
  g2[t + 256] = Lv[t + 768];
}

// Upper triangle of W W^T, W=[h1;h2] (16384 rows), 128x128 tiles, 8256
// blocks (r7 decode), 256 threads / 4 waves; wave w owns rows 32w..32w+31
// (2 row-frags) x 128 cols (8 col-frags) using the MX-scaled
// v_mfma_scale_f32_16x16x128_f8f6f4 (scales = 1.0 -> bit-identical to the
// fp8 path). ALL A fragments (8 Frag8 = 64 VGPR) are preloaded from global.
//
// NEW (this round): B tile staged in 4 K-chunks of 16 KB, double-buffered in
// 2x16 KB = 32 KB LDS (was one 64 KB stage). Counted-vmcnt pipeline (T3+T4):
// each wave issues 4 global_load_lds per chunk, waits vmcnt(4) (NOT 0 -> the
// next chunk stays in flight across the raw s_barrier), computes the chunk,
// barriers, then overwrites the retired buffer with chunk+2. This removes
// the serial stage->drain->compute structure (the ~20% barrier-drain class)
// and the 32 KB LDS + __launch_bounds__(256,3) register cap lifts occupancy
// from 2 to 3 blocks/CU. B fragments are consumed in pairs (16 VGPR live
// instead of 64) to fit the 170-reg budget.
__global__ __launch_bounds__(256, 3) void expsum_kernel(
    const uint8_t* __restrict__ h1p, const uint8_t* __restrict__ h2p,
    float* __restrict__ r1, float* __restrict__ r2,
    float* __restrict__ brow, float* __restrict__ bcol) {
  __shared__ __align__(16) uint8_t Bs[32768];   // 2 x 16 KB chunk buffers

  const int u = (blockIdx.x & 7) * 1032 + (blockIdx.x >> 3);  // 8256 = 8*1032
  int bj = (int)((sqrt(8.0 * (double)u + 1.0) - 1.0) * 0.5);
  if (bj * (bj + 1) / 2 > u) bj--;
  if ((bj + 1) * (bj + 2) / 2 <= u) bj++;
  const int bi = u - bj * (bj + 1) / 2;
  const bool diagb = (bi == bj);

  const uint8_t* Ap = (bi < 64) ? h1p : h2p;
  const uint8_t* Bp = (bj < 64) ? h1p : h2p;
  float* rowsOut = (bi < 64) ? ((bj < 64) ? r1 : brow) : r2;
  float* colsOut = (bj < 64) ? r1 : ((bi < 64) ? bcol : r2);
  const int iOutBase = (bi & 63) * 128;
  const int jOutBase = (bj & 63) * 128;

  const int t = threadIdx.x;
  const int w = t >> 6;         // wave 0..3: rows 32w..32w+31
  const int lane = t & 63;
  const int l16 = lane & 15;
  const int kq = lane >> 4;     // 0..3

  // ---- A: preload ALL fragments (2 row-groups x 4 ks), mid-anchored ----
  const uint8_t* Ag =
      Ap + ((size_t)((bi & 63) * 8 + w * 2)) * 8192 + (size_t)lane * 16 + 4096;
  Frag8 Af[2][4];
#pragma unroll
  for (int f = 0; f < 2; f++)
#pragma unroll
    for (int ks = 0; ks < 4; ks++) {
      const int ofs = f * 8192 + ks * 2048 - 4096;
      Af[f][ks].s.lo = *(const i32x4*)(Ag + ofs);
      Af[f][ks].s.hi = *(const i32x4*)(Ag + ofs + 1024);
    }
  __builtin_amdgcn_sched_barrier(0);   // pin A loads before the staged chunks

  const uint8_t* Bgp = Bp + (size_t)(bj & 63) * 65536;

  // Chunk ks (16 KB) in global: frag fn's unit at fn*8192 + ks*2048.
  // In the chunk buffer: fn*2048 + rem (rem in [0,2048) = lane-major halves).
  // Wave-uniform-base + lane*16 holds for the LDS dest (cb = (r*256+t)*16).
#define STAGE(KS, BUFOFS)                                                   \
  do {                                                                      \
    _Pragma("unroll") for (int r_ = 0; r_ < 4; r_++) {                      \
      const int cb_ = (r_ * 256 + t) * 16;                                  \
      gload_lds16(Bgp + ((cb_ >> 11) << 13) + (KS)*2048 + (cb_ & 2047),     \
                  Bs + (BUFOFS) + cb_);                                     \
    }                                                                       \
  } while (0)

  // B fragments consumed in pairs (16 VGPR live) to stay under the
  // __launch_bounds__(256,3) register budget.
#define COMPUTE_CHUNK(KS, BUFOFS)                                           \
  do {                                                                      \
    const uint8_t* Bc_ = (const uint8_t*)Bs + (BUFOFS) + lane * 16;         \
    _Pragma("unroll") for (int fp_ = 0; fp_ < 4; fp_++) {                   \
      Frag8 B0_, B1_;                                                       \
      B0_.s.lo = *(const i32x4*)(Bc_ + (2 * fp_ + 0) * 2048);               \
      B0_.s.hi = *(const i32x4*)(Bc_ + (2 * fp_ + 0) * 2048 + 1024);        \
      B1_.s.lo = *(const i32x4*)(Bc_ + (2 * fp_ + 1) * 2048);               \
      B1_.s.hi = *(const i32x4*)(Bc_ + (2 * fp_ + 1) * 2048 + 1024);        \
      _Pragma("unroll") for (int fm_ = 0; fm_ < 2; fm_++) {                 \
        acc[fm_][2 * fp_ + 0] =                                             \
            __builtin_amdgcn_mfma_scale_f32_16x16x128_f8f6f4(               \
                Af[fm_][KS].v8, B0_.v8, acc[fm_][2 * fp_ + 0],              \
                0, 0, 0, 0x7F7F7F7F, 0, 0x7F7F7F7F);                        \
        acc[fm_][2 * fp_ + 1] =                                             \
            __builtin_amdgcn_mfma_scale_f32_16x16x128_f8f6f4(               \
                Af[fm_][KS].v8, B1_.v8, acc[fm_][2 * fp_ + 1],              \
                0, 0, 0, 0x7F7F7F7F, 0, 0x7F7F7F7F);                        \
      }                                                                     \
    }                                                                       \
  } while (0)

  // ---- prologue: stage chunks 0 and 1 (4 loads each per thread) ----
  STAGE(0, 0);
  STAGE(1, 16384);

  f32x4 acc[2][8];
#pragma unroll
  for (int a = 0; a < 2; a++)
#pragma unroll
    for (int b = 0; b < 8; b++)
#pragma unroll
      for (int r = 0; r < 4; r++) acc[a][b][r] = 0.0f;

  // ---- counted-vmcnt chunk pipeline (raw barriers; never __syncthreads,
  //      which would drain vmcnt(0) and serialize the staging) ----
  // ks=0: chunk0 landed (c1 = newest 4 stays in flight)
  asm volatile("s_waitcnt vmcnt(4)" ::: "memory");
  __builtin_amdgcn_s_barrier();
  __builtin_amdgcn_sched_barrier(0);
  COMPUTE_CHUNK(0, 0);
  __builtin_amdgcn_sched_barrier(0);
  __builtin_amdgcn_s_barrier();        // all waves done reading buf0
  STAGE(2, 0);

  // ks=1
  asm volatile("s_waitcnt vmcnt(4)" ::: "memory");
  __builtin_amdgcn_s_barrier();
  __builtin_amdgcn_sched_barrier(0);
  COMPUTE_CHUNK(1, 16384);
  __builtin_amdgcn_sched_barrier(0);
  __builtin_amdgcn_s_barrier();        // all waves done reading buf1
  STAGE(3, 16384);

  // ks=2
  asm volatile("s_waitcnt vmcnt(4)" ::: "memory");
  __builtin_amdgcn_s_barrier();
  __builtin_amdgcn_sched_barrier(0);
  COMPUTE_CHUNK(2, 0);

  // ks=3 (last: drain)
  asm volatile("s_waitcnt vmcnt(0)" ::: "memory");
  __builtin_amdgcn_s_barrier();
  __builtin_amdgcn_sched_barrier(0);
  COMPUTE_CHUNK(3, 16384);

#undef STAGE
#undef COMPUTE_CHUNK

  // ---- Epilogue. C/D layout (shape-determined): col=lane&15, row=kq*4+reg ----
  float rowp[2][4];
  float colp[8];
#pragma unroll
  for (int fm = 0; fm < 2; fm++)
#pragma unroll
    for (int r = 0; r < 4; r++) rowp[fm][r] = 0.0f;
#pragma unroll
  for (int fn = 0; fn < 8; fn++) colp[fn] = 0.0f;

  if (!diagb) {
#pragma unroll
    for (int fm = 0; fm < 2; fm++)
#pragma unroll
      for (int fn = 0; fn < 8; fn++)
#pragma unroll
        for (int r = 0; r < 4; r++) {
          const float e = __expf(acc[fm][fn][r] * INV_TAU);
          rowp[fm][r] += e;
          colp[fn] += e;
        }
  } else {
    // within-tile indices (i0==j0): rows keep ti<=tj, cols keep ti<tj
#pragma unroll
    for (int fm = 0; fm < 2; fm++)
#pragma unroll
      for (int fn = 0; fn < 8; fn++)
#pragma unroll
        for (int r = 0; r < 4; r++) {
          const int ti = w * 32 + fm * 16 + kq * 4 + r;
          const int tj = fn * 16 + l16;
          const float e = __expf(acc[fm][fn][r] * INV_TAU);
          rowp[fm][r] += (ti <= tj) ? e : 0.0f;
          colp[fn] += (ti < tj) ? e : 0.0f;
        }
  }

  // reduction buffers alias into Bs — safe after all waves left the K-loop
  __syncthreads();
  float* lds_col = (float*)Bs;          // 128 floats, contended -> zero+atomic
  float* lds_row = lds_col + 128;       // 128 floats, unique -> plain store
  if (t < 128) lds_col[t] = 0.0f;
  __syncthreads();

  // Row sums: reduce across the 16 lanes (cols) sharing kq; unique dest per
  // (w,fm,kq,r) -> plain store.
#pragma unroll
  for (int fm = 0; fm < 2; fm++) {
#pragma unroll
    for (int r = 0; r < 4; r++) {
      float v = rowp[fm][r];
      v += __shfl_xor(v, 1);
      v += __shfl_xor(v, 2);
      v += __shfl_xor(v, 4);
      v += __shfl_xor(v, 8);
      if (l16 == 0) lds_row[w * 32 + fm * 16 + kq * 4 + r] = v;
    }
  }
  // Col sums: reduce across the 4 kq groups; 4 waves contend per col.
#pragma unroll
  for (int fn = 0; fn < 8; fn++) {
    float v = colp[fn];
    v += __shfl_xor(v, 16);
    v += __shfl_xor(v, 32);
    if (kq == 0) atomicAdd(&lds_col[fn * 16 + l16], v);
  }
  __syncthreads();

  if (t < 128) atomicAdd(&rowsOut[iOutBase + t], lds_row[t]);
  else         atomicAdd(&colsOut[jOutBase + (t - 128)], lds_col[t - 128]);
}

__global__ __launch_bounds__(256) void finalize_kernel(
    const float* __restrict__ r1, const float* __restrict__ r2,
    const float* __restrict__ brow, const float* __restrict__ bcol,
    const float* __restrict__ dvec, float* __restrict__ out) {
  const int i = blockIdx.x * 256 + threadIdx.x;
  const float den1 = r1[i] + brow[i] - EXP5;
  const float den2 = r2[i] + bcol[i] - EXP5;
  float v = 0.5f * (logf(den1) + logf(den2)) - INV_TAU * dvec[i];
  for (int m = 32; m; m >>= 1) v += __shfl_xor(v, m);
  __shared__ float red[4];
  const int wave = threadIdx.x >> 6;
  if ((threadIdx.x & 63) == 0) red[wave] = v;
  __syncthreads();
  if (threadIdx.x == 0) atomicAdd(out, red[0] + red[1] + red[2] + red[3]);
}

extern "C" void kernel_launch(void* const* d_in, const int* in_sizes, int n_in,
                              void* d_out, int out_size, void* d_ws, size_t ws_size,
                              hipStream_t stream) {
  const float* z1 = (const float*)d_in[0];
  const float* z2 = (const float*)d_in[1];
  float* out = (float*)d_out;

  char* ws = (char*)d_ws;
  uint8_t* h1p = (uint8_t*)ws;                 // 4 MiB fp8 K128-packed
  uint8_t* h2p = (uint8_t*)(ws + (4u << 20));  // 4 MiB
  float* r1   = (float*)(ws + (8u << 20));
  float* r2   = r1 + N_ROWS;
  float* brow = r2 + N_ROWS;
  float* bcol = brow + N_ROWS;
  float* dvec = bcol + N_ROWS;

  normalize_kernel<<<N_ROWS / 16, 256, 0, stream>>>(
      z1, z2, h1p, h2p, dvec, r1, r2, brow, bcol, out);
  expsum_kernel<<<8256, 256, 0, stream>>>(h1p, h2p, r1, r2, brow, bcol);
  finalize_kernel<<<N_ROWS / 256, 256, 0, stream>>>(r1, r2, brow, bcol, dvec, out);
}